// Round 5
// baseline (212.890 us; speedup 1.0000x reference)
//
#include <hip/hip_runtime.h>
#include <hip/hip_bf16.h>

// B=1024, N=96/branch, D=512.
// h1[b,n,:] = relu(U[b] + e[b,n]*T[n] + b1);  U=img@W1[:512], T=text@W1[512:]
// m2[b] = mean_n relu(h1@W2 + b2);  out = m2@W3 + b3
// prep v3 (576 blocks): sims 256 blk x 4 imgs | U gemm 256 blk 32x64 | T gemm 48 blk
//   | W2T transpose 16 blk.  All overlap in one launch.
// branch_mlp5: 512-thread blocks (8 waves x 32 cols) -> 48 acc regs/wave ->
//   4 waves/SIMD occupancy; dbuf sH, one barrier per 64-K tile, reg prefetch.

typedef __attribute__((ext_vector_type(8))) short short8;
typedef __attribute__((ext_vector_type(4))) float floatx4;
typedef __attribute__((ext_vector_type(4))) unsigned int uint4v;

__device__ __forceinline__ unsigned short f2bf(float x) {
    unsigned int u = __float_as_uint(x);
    u += 0x7fffu + ((u >> 16) & 1u);   // RNE
    return (unsigned short)(u >> 16);
}
__device__ __forceinline__ float bf2f(unsigned short u) {
    return __uint_as_float(((unsigned int)u) << 16);
}

// ---- 32x64-tile fp32 GEMM (K=512): C[32 rows][64 cols], LDS sAT[32][34] -------
template <bool BF16OUT>
__device__ __forceinline__ void gemm32(
    const float* __restrict__ A0, const float* __restrict__ A1, int rows0,
    const float* __restrict__ Bm, float* __restrict__ Cf,
    unsigned short* __restrict__ Cb, int mt, int nt, float* sAT, int t) {
    int r0 = mt * 32, c0 = nt * 64;
    int rg = t >> 4, cg = t & 15;          // output: rows rg*2+{0,1}, cols cg*4
    int lrow = t >> 3, k4 = (t & 7) * 4;   // loader: row lrow, k offset k4
    int gr = r0 + lrow;
    const float* Ap = (gr < rows0) ? (A0 + gr * 512) : (A1 + (gr - rows0) * 512);
    float acc[2][4];
#pragma unroll
    for (int r = 0; r < 2; r++)
#pragma unroll
        for (int c = 0; c < 4; c++) acc[r][c] = 0.f;
    const float* Bp = Bm + c0 + cg * 4;
    for (int k0 = 0; k0 < 512; k0 += 32) {
        __syncthreads();
        float4 av = *(const float4*)(Ap + k0 + k4);
        sAT[(k4 + 0) * 34 + lrow] = av.x;
        sAT[(k4 + 1) * 34 + lrow] = av.y;
        sAT[(k4 + 2) * 34 + lrow] = av.z;
        sAT[(k4 + 3) * 34 + lrow] = av.w;
        __syncthreads();
#pragma unroll 8
        for (int kk = 0; kk < 32; kk++) {
            float a0 = sAT[kk * 34 + rg * 2];
            float a1 = sAT[kk * 34 + rg * 2 + 1];
            float4 bv = *(const float4*)(Bp + (k0 + kk) * 512);
            acc[0][0] = fmaf(a0, bv.x, acc[0][0]); acc[0][1] = fmaf(a0, bv.y, acc[0][1]);
            acc[0][2] = fmaf(a0, bv.z, acc[0][2]); acc[0][3] = fmaf(a0, bv.w, acc[0][3]);
            acc[1][0] = fmaf(a1, bv.x, acc[1][0]); acc[1][1] = fmaf(a1, bv.y, acc[1][1]);
            acc[1][2] = fmaf(a1, bv.z, acc[1][2]); acc[1][3] = fmaf(a1, bv.w, acc[1][3]);
        }
    }
    int rr = r0 + rg * 2, cc = c0 + cg * 4;
#pragma unroll
    for (int r = 0; r < 2; r++) {
        if (BF16OUT) {
            unsigned long long pk =
                (unsigned long long)f2bf(acc[r][0]) | ((unsigned long long)f2bf(acc[r][1]) << 16) |
                ((unsigned long long)f2bf(acc[r][2]) << 32) | ((unsigned long long)f2bf(acc[r][3]) << 48);
            *(unsigned long long*)(Cb + (rr + r) * 512 + cc) = pk;
        } else {
            *(float4*)(Cf + (rr + r) * 512 + cc) = make_float4(acc[r][0], acc[r][1], acc[r][2], acc[r][3]);
        }
    }
}

// ---- prep: [0,256) sims(4 imgs) | [256,512) U | [512,560) T | [560,576) W2T ----
__global__ __launch_bounds__(256) void prep_kernel(
    const float* __restrict__ img, const float* __restrict__ tn,
    const float* __restrict__ ta, const float* __restrict__ ls,
    const float* __restrict__ W1, const float* __restrict__ W2,
    float* __restrict__ e_ws, float* __restrict__ U_ws,
    unsigned short* __restrict__ Tb, unsigned short* __restrict__ W2T) {
    __shared__ __align__(16) float smem[8704];
    int idx = blockIdx.x;
    int t = threadIdx.x;

    if (idx < 256) {
        // ---- sims+softmax+e for images [4*idx, 4*idx+4) ----
        int bi0 = idx * 4;
        float* sImg = smem;             // 4 x 516 (padded)
        float* sS   = smem + 2064;      // 4 x 192
        float* sMx  = smem + 2832;      // 8 (i*2+br)
        float* sSum = smem + 2840;      // 8
#pragma unroll
        for (int p = 0; p < 2; p++) {
            int i4 = t + 256 * p;              // 0..511
            int i = i4 >> 7, k4 = (i4 & 127) * 4;
            float4 v = *(const float4*)(img + (bi0 + i) * 512 + k4);
            sImg[i * 516 + k4 + 0] = v.x; sImg[i * 516 + k4 + 1] = v.y;
            sImg[i * 516 + k4 + 2] = v.z; sImg[i * 516 + k4 + 3] = v.w;
        }
        __syncthreads();
        float scale = __expf(ls[0]);
        int i = t & 3, n0 = (t >> 2) * 3;
        const float* txp[3];
#pragma unroll
        for (int r = 0; r < 3; r++) {
            int n = n0 + r;
            txp[r] = (n < 96) ? (tn + n * 512) : (ta + (n - 96) * 512);
        }
        float d0 = 0.f, d1 = 0.f, d2 = 0.f;
        const float* ib = &sImg[i * 516];
#pragma unroll 4
        for (int k4 = 0; k4 < 512; k4 += 4) {
            float4 iv = *(const float4*)(ib + k4);
            float4 a = *(const float4*)(txp[0] + k4);
            float4 b = *(const float4*)(txp[1] + k4);
            float4 c = *(const float4*)(txp[2] + k4);
            d0 += iv.x * a.x + iv.y * a.y + iv.z * a.z + iv.w * a.w;
            d1 += iv.x * b.x + iv.y * b.y + iv.z * b.z + iv.w * b.w;
            d2 += iv.x * c.x + iv.y * c.y + iv.z * c.z + iv.w * c.w;
        }
        sS[i * 192 + n0 + 0] = d0 * scale;
        sS[i * 192 + n0 + 1] = d1 * scale;
        sS[i * 192 + n0 + 2] = d2 * scale;
        __syncthreads();
        if (t < 8) {
            int ii = t >> 1, brx = t & 1;
            const float* base = &sS[ii * 192 + brx * 96];
            float m = -1e30f;
            for (int n = 0; n < 96; n++) m = fmaxf(m, base[n]);
            float s = 0.f;
            for (int n = 0; n < 96; n++) s += __expf(base[n] - m);
            sMx[t] = m; sSum[t] = s;
        }
        __syncthreads();
#pragma unroll
        for (int p = 0; p < 3; p++) {
            int j = t + 256 * p;               // 0..767
            int ii = j & 3, n = j >> 2;        // n 0..191
            int brx = (n >= 96) ? 1 : 0;
            int nn = n - brx * 96;
            float w = __expf(sS[ii * 192 + n] - sMx[ii * 2 + brx]) / sSum[ii * 2 + brx];
            e_ws[(brx * 1024 + bi0 + ii) * 96 + nn] = __expf(w);
        }
    } else if (idx < 512) {
        int i2 = idx - 256;                    // 32 mt x 8 nt
        gemm32<false>(img, img, 1 << 20, W1, U_ws, nullptr, i2 >> 3, i2 & 7, smem, t);
    } else if (idx < 560) {
        int i2 = idx - 512;                    // 6 mt x 8 nt (192 rows: tn|ta)
        gemm32<true>(tn, ta, 96, W1 + 512 * 512, nullptr, Tb, i2 >> 3, i2 & 7, smem, t);
    } else {
        // ---- W2 [512,256] -> W2T [256,512] bf16, k-chunk of 32 per block ----
        int ci = idx - 560;
        int k0 = ci * 32;
        float* sWT = smem;                     // 256 x 33
        int kr = t >> 3, n0 = (t & 7) * 32;
#pragma unroll
        for (int c = 0; c < 8; c++) {
            float4 v = *(const float4*)(W2 + (k0 + kr) * 256 + n0 + c * 4);
            sWT[(n0 + c * 4 + 0) * 33 + kr] = v.x;
            sWT[(n0 + c * 4 + 1) * 33 + kr] = v.y;
            sWT[(n0 + c * 4 + 2) * 33 + kr] = v.z;
            sWT[(n0 + c * 4 + 3) * 33 + kr] = v.w;
        }
        __syncthreads();
        unsigned short pk[32];
#pragma unroll
        for (int k = 0; k < 32; k++) pk[k] = f2bf(sWT[t * 33 + k]);
#pragma unroll
        for (int g = 0; g < 4; g++) {
            uint4v u;
#pragma unroll
            for (int c = 0; c < 4; c++)
                u[c] = (unsigned int)pk[g * 8 + 2 * c] | ((unsigned int)pk[g * 8 + 2 * c + 1] << 16);
            *(uint4v*)(W2T + t * 512 + k0 + g * 8) = u;
        }
    }
}

// ---- branch_mlp5: 512 thr, 8 waves x 32 cols; dbuf sH; 1 barrier/64-K tile -----
// grid (1024, 2). Rows 96, cols 256, K=512.
__global__ __launch_bounds__(512, 4) void branch_mlp5(
    const float* __restrict__ U, const unsigned short* __restrict__ Tb,
    const float* __restrict__ e_all, const unsigned short* __restrict__ W2T,
    const float* __restrict__ b1, const float* __restrict__ b2,
    const float* __restrict__ W3, const float* __restrict__ b3,
    float* __restrict__ out) {
    int b = blockIdx.x, br = blockIdx.y;
    const unsigned short* T = Tb + br * (96 * 512);

    __shared__ float sUb[512];
    __shared__ float sE[96];
    __shared__ __align__(16) unsigned short sH[2][96][88];
    __shared__ float sM2[256];
    __shared__ float sPart[512];

    int t = threadIdx.x;
    sUb[t] = U[b * 512 + t] + b1[t];
    if (t < 96) sE[t] = e_all[(br * 1024 + b) * 96 + t];
    __syncthreads();

    const int wave = t >> 6, lane = t & 63;
    const int frow = lane & 15, fkq = (lane >> 4) * 8;
    const int ncol0 = wave * 32;
    const int srow = t >> 3;          // 0..63
    const int skc = (t & 7) * 8;      // 0..56
    const bool two = (srow < 32);     // wave-uniform: waves 0-3 stage 2 rows

    const floatx4 fz = {0.f, 0.f, 0.f, 0.f};
    floatx4 acc[6][2];
#pragma unroll
    for (int mt = 0; mt < 6; mt++) {
        acc[mt][0] = fz; acc[mt][1] = fz;
    }

    int trow1 = srow + 64;
    float ev0 = sE[srow], ev1 = two ? sE[trow1] : 0.f;
    short8 tv0 = *(const short8*)(T + srow * 512 + skc);
    short8 tv1 = two ? *(const short8*)(T + trow1 * 512 + skc) : tv0;

    const unsigned short* Bbase = W2T + (ncol0 + frow) * 512 + fkq;
    short8 bpre[2];
    bpre[0] = *(const short8*)(Bbase);
    bpre[1] = *(const short8*)(Bbase + 16 * 512);

#pragma unroll
    for (int s = 0; s < 8; s++) {
        int k0 = s * 64;
        float4 u0 = *(const float4*)(&sUb[k0 + skc]);
        float4 u1 = *(const float4*)(&sUb[k0 + skc + 4]);
        float ua[8] = {u0.x, u0.y, u0.z, u0.w, u1.x, u1.y, u1.z, u1.w};
        // stage row srow
        {
            uint4v pk;
#pragma unroll
            for (int jj = 0; jj < 4; jj++) {
                float f0 = fmaxf(fmaf(ev0, bf2f((unsigned short)tv0[2 * jj]), ua[2 * jj]), 0.f);
                float f1 = fmaxf(fmaf(ev0, bf2f((unsigned short)tv0[2 * jj + 1]), ua[2 * jj + 1]), 0.f);
                __hip_bfloat162 h2 = __float22bfloat162_rn(make_float2(f0, f1));
                unsigned int bits; __builtin_memcpy(&bits, &h2, 4);
                pk[jj] = bits;
            }
            *(uint4v*)(&sH[s & 1][srow][skc]) = pk;
        }
        if (two) {   // stage row srow+64 (waves 0-3 only, wave-uniform)
            uint4v pk;
#pragma unroll
            for (int jj = 0; jj < 4; jj++) {
                float f0 = fmaxf(fmaf(ev1, bf2f((unsigned short)tv1[2 * jj]), ua[2 * jj]), 0.f);
                float f1 = fmaxf(fmaf(ev1, bf2f((unsigned short)tv1[2 * jj + 1]), ua[2 * jj + 1]), 0.f);
                __hip_bfloat162 h2 = __float22bfloat162_rn(make_float2(f0, f1));
                unsigned int bits; __builtin_memcpy(&bits, &h2, 4);
                pk[jj] = bits;
            }
            *(uint4v*)(&sH[s & 1][trow1][skc]) = pk;
        }
        short8 bcur0 = bpre[0], bcur1 = bpre[1];
        if (s < 7) {   // prefetch next tile before the barrier
            tv0 = *(const short8*)(T + srow * 512 + k0 + 64 + skc);
            if (two) tv1 = *(const short8*)(T + trow1 * 512 + k0 + 64 + skc);
            bpre[0] = *(const short8*)(Bbase + k0 + 64);
            bpre[1] = *(const short8*)(Bbase + 16 * 512 + k0 + 64);
        }
        __syncthreads();
        short8 b1f0 = *(const short8*)(Bbase + k0 + 32);
        short8 b1f1 = *(const short8*)(Bbase + 16 * 512 + k0 + 32);
#pragma unroll
        for (int mt = 0; mt < 6; mt++) {
            short8 afr = *(const short8*)(&sH[s & 1][mt * 16 + frow][fkq]);
            acc[mt][0] = __builtin_amdgcn_mfma_f32_16x16x32_bf16(afr, bcur0, acc[mt][0], 0, 0, 0);
            acc[mt][1] = __builtin_amdgcn_mfma_f32_16x16x32_bf16(afr, bcur1, acc[mt][1], 0, 0, 0);
        }
#pragma unroll
        for (int mt = 0; mt < 6; mt++) {
            short8 afr = *(const short8*)(&sH[s & 1][mt * 16 + frow][32 + fkq]);
            acc[mt][0] = __builtin_amdgcn_mfma_f32_16x16x32_bf16(afr, b1f0, acc[mt][0], 0, 0, 0);
            acc[mt][1] = __builtin_amdgcn_mfma_f32_16x16x32_bf16(afr, b1f1, acc[mt][1], 0, 0, 0);
        }
    }

    // epilogue 1: +b2, relu, mean over 96 rows -> sM2[256]
#pragma unroll
    for (int j = 0; j < 2; j++) {
        int col = ncol0 + j * 16 + frow;
        float bb = b2[col];
        float s = 0.f;
#pragma unroll
        for (int mt = 0; mt < 6; mt++)
#pragma unroll
            for (int r = 0; r < 4; r++)
                s += fmaxf(acc[mt][j][r] + bb, 0.f);
        s += __shfl_xor(s, 16);
        s += __shfl_xor(s, 32);
        if (lane < 16) sM2[col] = s * (1.0f / 96.0f);
    }
    __syncthreads();

    // epilogue 2: out = sM2 @ W3 + b3  (256x128), K split across 4 quarter-blocks
    int col = t & 127, kq = t >> 7;
    const float* w3p = W3 + (kq * 64) * 128 + col;
    const float* mp = sM2 + kq * 64;
    float o = 0.f;
#pragma unroll 8
    for (int k = 0; k < 64; k++) o = fmaf(mp[k], w3p[k * 128], o);
    sPart[t] = o;
    __syncthreads();
    if (t < 128)
        out[(br * 1024 + b) * 128 + t] =
            sPart[t] + sPart[t + 128] + sPart[t + 256] + sPart[t + 384] + b3[t];
}

// ---- launch --------------------------------------------------------------------
extern "C" void kernel_launch(void* const* d_in, const int* in_sizes, int n_in,
                              void* d_out, int out_size, void* d_ws, size_t ws_size,
                              hipStream_t stream) {
    const float* img = (const float*)d_in[0];
    const float* tn  = (const float*)d_in[1];
    const float* ta  = (const float*)d_in[2];
    const float* ls  = (const float*)d_in[3];
    const float* W1  = (const float*)d_in[4];
    const float* b1  = (const float*)d_in[5];
    const float* W2  = (const float*)d_in[6];
    const float* b2  = (const float*)d_in[7];
    const float* W3  = (const float*)d_in[8];
    const float* b3  = (const float*)d_in[9];
    float* out = (float*)d_out;
    float* ws  = (float*)d_ws;

    float* e_ws = ws;                                        // 196608 f
    float* U_ws = ws + 196608;                               // 524288 f
    unsigned short* Tb  = (unsigned short*)(ws + 720896);    // 192*512 bf16
    unsigned short* W2T = (unsigned short*)(ws + 770048);    // 256*512 bf16

    prep_kernel<<<576, 256, 0, stream>>>(img, tn, ta, ls, W1, W2, e_ws, U_ws, Tb, W2T);
    branch_mlp5<<<dim3(1024, 2), 512, 0, stream>>>(U_ws, Tb, e_ws, W2T, b1, b2, W3, b3, out);
}

// Round 6
// 193.293 us; speedup vs baseline: 1.1014x; 1.1014x over previous
//
#include <hip/hip_runtime.h>
#include <hip/hip_bf16.h>

// B=1024, N=96/branch, D=512.
// h1[b,n,:] = relu(U[b] + e[b,n]*T[n] + b1);  U=img@W1[:512], T=text@W1[512:]
// m2[b] = mean_n relu(h1@W2 + b2);  out = m2@W3 + b3
// prep (576 blk): sims | U gemm | T gemm(bf16) | W2 -> MFMA-B-fragment layout bf16.
// branch_mlp6: 48 rows/block (grid 1024x2x2) -> acc 48 regs -> 4 waves/SIMD;
//   XOR-swizzled sH (no pad, conflict-free); B-frags 1KB coalesced wave-loads.
// out_kernel: m2 = (p0+p1)/96; out = m2@W3 + b3.

typedef __attribute__((ext_vector_type(8))) short short8;
typedef __attribute__((ext_vector_type(4))) float floatx4;
typedef __attribute__((ext_vector_type(4))) unsigned int uint4v;

__device__ __forceinline__ unsigned short f2bf(float x) {
    unsigned int u = __float_as_uint(x);
    u += 0x7fffu + ((u >> 16) & 1u);   // RNE
    return (unsigned short)(u >> 16);
}
__device__ __forceinline__ float bf2f(unsigned short u) {
    return __uint_as_float(((unsigned int)u) << 16);
}

// ---- 32x64-tile fp32 GEMM (K=512): C[32 rows][64 cols], LDS sAT[32][34] -------
template <bool BF16OUT>
__device__ __forceinline__ void gemm32(
    const float* __restrict__ A0, const float* __restrict__ A1, int rows0,
    const float* __restrict__ Bm, float* __restrict__ Cf,
    unsigned short* __restrict__ Cb, int mt, int nt, float* sAT, int t) {
    int r0 = mt * 32, c0 = nt * 64;
    int rg = t >> 4, cg = t & 15;
    int lrow = t >> 3, k4 = (t & 7) * 4;
    int gr = r0 + lrow;
    const float* Ap = (gr < rows0) ? (A0 + gr * 512) : (A1 + (gr - rows0) * 512);
    float acc[2][4];
#pragma unroll
    for (int r = 0; r < 2; r++)
#pragma unroll
        for (int c = 0; c < 4; c++) acc[r][c] = 0.f;
    const float* Bp = Bm + c0 + cg * 4;
    for (int k0 = 0; k0 < 512; k0 += 32) {
        __syncthreads();
        float4 av = *(const float4*)(Ap + k0 + k4);
        sAT[(k4 + 0) * 34 + lrow] = av.x;
        sAT[(k4 + 1) * 34 + lrow] = av.y;
        sAT[(k4 + 2) * 34 + lrow] = av.z;
        sAT[(k4 + 3) * 34 + lrow] = av.w;
        __syncthreads();
#pragma unroll 8
        for (int kk = 0; kk < 32; kk++) {
            float a0 = sAT[kk * 34 + rg * 2];
            float a1 = sAT[kk * 34 + rg * 2 + 1];
            float4 bv = *(const float4*)(Bp + (k0 + kk) * 512);
            acc[0][0] = fmaf(a0, bv.x, acc[0][0]); acc[0][1] = fmaf(a0, bv.y, acc[0][1]);
            acc[0][2] = fmaf(a0, bv.z, acc[0][2]); acc[0][3] = fmaf(a0, bv.w, acc[0][3]);
            acc[1][0] = fmaf(a1, bv.x, acc[1][0]); acc[1][1] = fmaf(a1, bv.y, acc[1][1]);
            acc[1][2] = fmaf(a1, bv.z, acc[1][2]); acc[1][3] = fmaf(a1, bv.w, acc[1][3]);
        }
    }
    int rr = r0 + rg * 2, cc = c0 + cg * 4;
#pragma unroll
    for (int r = 0; r < 2; r++) {
        if (BF16OUT) {
            unsigned long long pk =
                (unsigned long long)f2bf(acc[r][0]) | ((unsigned long long)f2bf(acc[r][1]) << 16) |
                ((unsigned long long)f2bf(acc[r][2]) << 32) | ((unsigned long long)f2bf(acc[r][3]) << 48);
            *(unsigned long long*)(Cb + (rr + r) * 512 + cc) = pk;
        } else {
            *(float4*)(Cf + (rr + r) * 512 + cc) = make_float4(acc[r][0], acc[r][1], acc[r][2], acc[r][3]);
        }
    }
}

// ---- prep: [0,256) sims(4 imgs) | [256,512) U | [512,560) T | [560,576) W2Tf ---
__global__ __launch_bounds__(256) void prep_kernel(
    const float* __restrict__ img, const float* __restrict__ tn,
    const float* __restrict__ ta, const float* __restrict__ ls,
    const float* __restrict__ W1, const float* __restrict__ W2,
    float* __restrict__ e_ws, float* __restrict__ U_ws,
    unsigned short* __restrict__ Tb, unsigned short* __restrict__ W2Tf) {
    __shared__ __align__(16) float smem[8704];
    int idx = blockIdx.x;
    int t = threadIdx.x;

    if (idx < 256) {
        // sims+softmax+e for images [4*idx, 4*idx+4)
        int bi0 = idx * 4;
        float* sImg = smem;             // 4 x 516
        float* sS   = smem + 2064;      // 4 x 192
        float* sMx  = smem + 2832;      // 8
        float* sSum = smem + 2840;      // 8
#pragma unroll
        for (int p = 0; p < 2; p++) {
            int i4 = t + 256 * p;
            int i = i4 >> 7, k4 = (i4 & 127) * 4;
            float4 v = *(const float4*)(img + (bi0 + i) * 512 + k4);
            sImg[i * 516 + k4 + 0] = v.x; sImg[i * 516 + k4 + 1] = v.y;
            sImg[i * 516 + k4 + 2] = v.z; sImg[i * 516 + k4 + 3] = v.w;
        }
        __syncthreads();
        float scale = __expf(ls[0]);
        int i = t & 3, n0 = (t >> 2) * 3;
        const float* txp[3];
#pragma unroll
        for (int r = 0; r < 3; r++) {
            int n = n0 + r;
            txp[r] = (n < 96) ? (tn + n * 512) : (ta + (n - 96) * 512);
        }
        float d0 = 0.f, d1 = 0.f, d2 = 0.f;
        const float* ib = &sImg[i * 516];
#pragma unroll 4
        for (int k4 = 0; k4 < 512; k4 += 4) {
            float4 iv = *(const float4*)(ib + k4);
            float4 a = *(const float4*)(txp[0] + k4);
            float4 b = *(const float4*)(txp[1] + k4);
            float4 c = *(const float4*)(txp[2] + k4);
            d0 += iv.x * a.x + iv.y * a.y + iv.z * a.z + iv.w * a.w;
            d1 += iv.x * b.x + iv.y * b.y + iv.z * b.z + iv.w * b.w;
            d2 += iv.x * c.x + iv.y * c.y + iv.z * c.z + iv.w * c.w;
        }
        sS[i * 192 + n0 + 0] = d0 * scale;
        sS[i * 192 + n0 + 1] = d1 * scale;
        sS[i * 192 + n0 + 2] = d2 * scale;
        __syncthreads();
        if (t < 8) {
            int ii = t >> 1, brx = t & 1;
            const float* base = &sS[ii * 192 + brx * 96];
            float m = -1e30f;
            for (int n = 0; n < 96; n++) m = fmaxf(m, base[n]);
            float s = 0.f;
            for (int n = 0; n < 96; n++) s += __expf(base[n] - m);
            sMx[t] = m; sSum[t] = s;
        }
        __syncthreads();
#pragma unroll
        for (int p = 0; p < 3; p++) {
            int j = t + 256 * p;
            int ii = j & 3, n = j >> 2;
            int brx = (n >= 96) ? 1 : 0;
            int nn = n - brx * 96;
            float w = __expf(sS[ii * 192 + n] - sMx[ii * 2 + brx]) / sSum[ii * 2 + brx];
            e_ws[(brx * 1024 + bi0 + ii) * 96 + nn] = __expf(w);
        }
    } else if (idx < 512) {
        int i2 = idx - 256;
        gemm32<false>(img, img, 1 << 20, W1, U_ws, nullptr, i2 >> 3, i2 & 7, smem, t);
    } else if (idx < 560) {
        int i2 = idx - 512;
        gemm32<true>(tn, ta, 96, W1 + 512 * 512, nullptr, Tb, i2 >> 3, i2 & 7, smem, t);
    } else {
        // W2 [512][256] -> W2Tf MFMA-B-fragment layout:
        // W2Tf[((kt*16 + nt)*64 + lane)*8 + jj] = bf16(W2[(kt*32 + (lane>>4)*8 + jj)][nt*16 + (lane&15)])
        int kt = idx - 560;               // 0..15, k-chunk of 32
        int k0 = kt * 32;
        float* sWT = smem;                // [256][33] n-major
        int kr = t >> 3, n0 = (t & 7) * 32;
#pragma unroll
        for (int c = 0; c < 8; c++) {
            float4 v = *(const float4*)(W2 + (k0 + kr) * 256 + n0 + c * 4);
            sWT[(n0 + c * 4 + 0) * 33 + kr] = v.x;
            sWT[(n0 + c * 4 + 1) * 33 + kr] = v.y;
            sWT[(n0 + c * 4 + 2) * 33 + kr] = v.z;
            sWT[(n0 + c * 4 + 3) * 33 + kr] = v.w;
        }
        __syncthreads();
        int lane = t & 63;
        int kl = (lane >> 4) * 8;
#pragma unroll
        for (int it = 0; it < 4; it++) {
            int nt = it * 4 + (t >> 6);
            int n = nt * 16 + (lane & 15);
            uint4v u;
#pragma unroll
            for (int c = 0; c < 4; c++) {
                unsigned short lo = f2bf(sWT[n * 33 + kl + 2 * c]);
                unsigned short hi = f2bf(sWT[n * 33 + kl + 2 * c + 1]);
                u[c] = (unsigned int)lo | ((unsigned int)hi << 16);
            }
            *(uint4v*)(W2Tf + (((kt * 16 + nt) * 64) + lane) * 8) = u;
        }
    }
}

// ---- branch_mlp6: 48 rows/block; swizzled sH; partial m2 ----------------------
// grid (1024, 2, 2), block 256 (4 waves x 64 cols). K=512, BK=64, dbuf, 1 barrier.
__global__ __launch_bounds__(256, 4) void branch_mlp6(
    const float* __restrict__ U, const unsigned short* __restrict__ Tb,
    const float* __restrict__ e_all, const unsigned short* __restrict__ W2Tf,
    const float* __restrict__ b1, const float* __restrict__ b2,
    float* __restrict__ m2p) {
    int b = blockIdx.x, br = blockIdx.y, half = blockIdx.z;
    const unsigned short* T = Tb + br * (96 * 512) + half * (48 * 512);

    __shared__ float sUb[512];
    __shared__ float sE[48];
    __shared__ __align__(16) unsigned short sH[2][48 * 64];

    int t = threadIdx.x;
    sUb[t] = U[b * 512 + t] + b1[t];
    sUb[t + 256] = U[b * 512 + t + 256] + b1[t + 256];
    if (t < 48) sE[t] = e_all[(br * 1024 + b) * 96 + half * 48 + t];
    __syncthreads();

    const int wave = t >> 6, lane = t & 63;
    const int frow = lane & 15, fkq = (lane >> 4) * 8;
    const int f7 = frow & 7;
    const int srow = t >> 3;          // 0..31
    const int skc = (t & 7) * 8;      // 0..56
    const bool two = (t < 128);       // waves 0,1 also stage rows 32..47
    const int srow2 = 32 + (t >> 3);

    const floatx4 fz = {0.f, 0.f, 0.f, 0.f};
    floatx4 acc[3][4];
#pragma unroll
    for (int mt = 0; mt < 3; mt++)
#pragma unroll
        for (int j = 0; j < 4; j++) acc[mt][j] = fz;

    float ev0 = sE[srow];
    float ev1 = two ? sE[srow2] : 0.f;
    const int sw1 = skc ^ ((srow & 7) * 8);
    const int sw2 = skc ^ ((srow2 & 7) * 8);

    // B fragments: W2Tf[((kt*16 + nt)*64 + lane)*8], nt = wave*4 + j
    const unsigned short* Wf = W2Tf + (wave * 4 * 64 + lane) * 8;
    short8 bpre[4];
#pragma unroll
    for (int j = 0; j < 4; j++)
        bpre[j] = *(const short8*)(Wf + j * (64 * 8));   // kt = 0

#pragma unroll
    for (int s = 0; s < 8; s++) {
        int k0 = s * 64;
        unsigned short* sHb = sH[s & 1];
        // ---- stage h1 tile (rows srow [,srow2], k = k0+skc..+8) ----
        float4 u0 = *(const float4*)(&sUb[k0 + skc]);
        float4 u1 = *(const float4*)(&sUb[k0 + skc + 4]);
        float ua[8] = {u0.x, u0.y, u0.z, u0.w, u1.x, u1.y, u1.z, u1.w};
        short8 tv0 = *(const short8*)(T + srow * 512 + k0 + skc);
        {
            uint4v pk;
#pragma unroll
            for (int jj = 0; jj < 4; jj++) {
                float f0 = fmaxf(fmaf(ev0, bf2f((unsigned short)tv0[2 * jj]), ua[2 * jj]), 0.f);
                float f1 = fmaxf(fmaf(ev0, bf2f((unsigned short)tv0[2 * jj + 1]), ua[2 * jj + 1]), 0.f);
                __hip_bfloat162 h2 = __float22bfloat162_rn(make_float2(f0, f1));
                unsigned int bits; __builtin_memcpy(&bits, &h2, 4);
                pk[jj] = bits;
            }
            *(uint4v*)(&sHb[srow * 64 + sw1]) = pk;
        }
        if (two) {
            short8 tv1 = *(const short8*)(T + srow2 * 512 + k0 + skc);
            uint4v pk;
#pragma unroll
            for (int jj = 0; jj < 4; jj++) {
                float f0 = fmaxf(fmaf(ev1, bf2f((unsigned short)tv1[2 * jj]), ua[2 * jj]), 0.f);
                float f1 = fmaxf(fmaf(ev1, bf2f((unsigned short)tv1[2 * jj + 1]), ua[2 * jj + 1]), 0.f);
                __hip_bfloat162 h2 = __float22bfloat162_rn(make_float2(f0, f1));
                unsigned int bits; __builtin_memcpy(&bits, &h2, 4);
                pk[jj] = bits;
            }
            *(uint4v*)(&sHb[srow2 * 64 + sw2]) = pk;
        }
        __syncthreads();   // drains staging writes (+ any loads) once per tile
        // ---- ks=1 B-frags issue now, consumed after ks=0 MFMAs ----
        short8 b1f[4];
#pragma unroll
        for (int j = 0; j < 4; j++)
            b1f[j] = *(const short8*)(Wf + ((2 * s + 1) * 16 + j) * (64 * 8));
        // ---- ks=0 MFMAs (bpre already in regs) ----
        const int ka0 = (((fkq >> 3) ^ f7) << 3);
        const int ka1 = (((4 + (fkq >> 3)) ^ f7) << 3);
#pragma unroll
        for (int mt = 0; mt < 3; mt++) {
            short8 afr = *(const short8*)(&sHb[(mt * 16 + frow) * 64 + ka0]);
#pragma unroll
            for (int j = 0; j < 4; j++)
                acc[mt][j] = __builtin_amdgcn_mfma_f32_16x16x32_bf16(afr, bpre[j], acc[mt][j], 0, 0, 0);
        }
        // ---- reload bpre for next tile's ks=0 (under ks=1 MFMAs) ----
        if (s < 7) {
#pragma unroll
            for (int j = 0; j < 4; j++)
                bpre[j] = *(const short8*)(Wf + ((2 * s + 2) * 16 + j) * (64 * 8));
        }
        // ---- ks=1 MFMAs ----
#pragma unroll
        for (int mt = 0; mt < 3; mt++) {
            short8 afr = *(const short8*)(&sHb[(mt * 16 + frow) * 64 + ka1]);
#pragma unroll
            for (int j = 0; j < 4; j++)
                acc[mt][j] = __builtin_amdgcn_mfma_f32_16x16x32_bf16(afr, b1f[j], acc[mt][j], 0, 0, 0);
        }
    }

    // epilogue: +b2, relu, partial sum over 48 rows -> m2p[half][br][b][256]
#pragma unroll
    for (int j = 0; j < 4; j++) {
        int col = wave * 64 + j * 16 + frow;
        float bb = b2[col];
        float s = 0.f;
#pragma unroll
        for (int mt = 0; mt < 3; mt++)
#pragma unroll
            for (int r = 0; r < 4; r++)
                s += fmaxf(acc[mt][j][r] + bb, 0.f);
        s += __shfl_xor(s, 16);
        s += __shfl_xor(s, 32);
        if (lane < 16)
            m2p[(((half * 2 + br) * 1024) + b) * 256 + col] = s;
    }
}

// ---- out_kernel: m2 = (p0+p1)/96; out = m2@W3 + b3 ----------------------------
__global__ __launch_bounds__(128) void out_kernel(
    const float* __restrict__ m2p, const float* __restrict__ W3,
    const float* __restrict__ b3, float* __restrict__ out) {
    int b = blockIdx.x, br = blockIdx.y;
    int t = threadIdx.x;
    __shared__ float sM[256];
    const float* p0 = m2p + ((0 + br) * 1024 + b) * 256;
    const float* p1 = m2p + ((2 + br) * 1024 + b) * 256;
    sM[t]       = (p0[t]       + p1[t])       * (1.0f / 96.0f);
    sM[t + 128] = (p0[t + 128] + p1[t + 128]) * (1.0f / 96.0f);
    __syncthreads();
    float o = b3[t];
#pragma unroll 8
    for (int k = 0; k < 256; k++) o = fmaf(sM[k], W3[k * 128 + t], o);
    out[(br * 1024 + b) * 128 + t] = o;
}

// ---- launch --------------------------------------------------------------------
extern "C" void kernel_launch(void* const* d_in, const int* in_sizes, int n_in,
                              void* d_out, int out_size, void* d_ws, size_t ws_size,
                              hipStream_t stream) {
    const float* img = (const float*)d_in[0];
    const float* tn  = (const float*)d_in[1];
    const float* ta  = (const float*)d_in[2];
    const float* ls  = (const float*)d_in[3];
    const float* W1  = (const float*)d_in[4];
    const float* b1  = (const float*)d_in[5];
    const float* W2  = (const float*)d_in[6];
    const float* b2  = (const float*)d_in[7];
    const float* W3  = (const float*)d_in[8];
    const float* b3  = (const float*)d_in[9];
    float* out = (float*)d_out;
    float* ws  = (float*)d_ws;

    float* e_ws = ws;                                        // 196608 f
    float* U_ws = ws + 196608;                               // 524288 f
    unsigned short* Tb   = (unsigned short*)(ws + 720896);   // 192*512 bf16 (49152 f)
    unsigned short* W2Tf = (unsigned short*)(ws + 770048);   // 256*512 bf16 frag layout (65536 f)
    float* m2p = ws + 835584;                                // 4*1024*256 f (1048576 f)

    prep_kernel<<<576, 256, 0, stream>>>(img, tn, ta, ls, W1, W2, e_ws, U_ws, Tb, W2Tf);
    branch_mlp6<<<dim3(1024, 2, 2), 256, 0, stream>>>(U_ws, Tb, e_ws, W2Tf, b1, b2, m2p);
    out_kernel<<<dim3(1024, 2), 128, 0, stream>>>(m2p, W3, b3, out);
}

// Round 7
// 187.152 us; speedup vs baseline: 1.1375x; 1.0328x over previous
//
#include <hip/hip_runtime.h>
#include <hip/hip_bf16.h>

// B=1024, N=96/branch, D=512.
// h1[b,n,:] = relu(U[b] + e[b,n]*T[n] + b1);  U=img@W1[:512], T=text@W1[512:]
// m2[b] = mean_n relu(h1@W2 + b2);  out = m2@W3 + b3
// prep (576 blk): sims | U gemm | T gemm(bf16) | W2 -> MFMA-B-fragment layout bf16.
// branch_mlp7: mlp6 + load-at-top-of-region scheduling: all global loads issue
//   right after the barrier and complete under the MFMA stream -> vmcnt(0) at
//   the next barrier is nearly free.  One barrier per 64-K tile, dbuf sH.
// out_kernel: m2 = (p0+p1)/96; out = m2@W3 + b3.

typedef __attribute__((ext_vector_type(8))) short short8;
typedef __attribute__((ext_vector_type(4))) float floatx4;
typedef __attribute__((ext_vector_type(4))) unsigned int uint4v;

__device__ __forceinline__ unsigned short f2bf(float x) {
    unsigned int u = __float_as_uint(x);
    u += 0x7fffu + ((u >> 16) & 1u);   // RNE
    return (unsigned short)(u >> 16);
}
__device__ __forceinline__ float bf2f(unsigned short u) {
    return __uint_as_float(((unsigned int)u) << 16);
}

// ---- 32x64-tile fp32 GEMM (K=512): C[32 rows][64 cols], LDS sAT[32][34] -------
template <bool BF16OUT>
__device__ __forceinline__ void gemm32(
    const float* __restrict__ A0, const float* __restrict__ A1, int rows0,
    const float* __restrict__ Bm, float* __restrict__ Cf,
    unsigned short* __restrict__ Cb, int mt, int nt, float* sAT, int t) {
    int r0 = mt * 32, c0 = nt * 64;
    int rg = t >> 4, cg = t & 15;
    int lrow = t >> 3, k4 = (t & 7) * 4;
    int gr = r0 + lrow;
    const float* Ap = (gr < rows0) ? (A0 + gr * 512) : (A1 + (gr - rows0) * 512);
    float acc[2][4];
#pragma unroll
    for (int r = 0; r < 2; r++)
#pragma unroll
        for (int c = 0; c < 4; c++) acc[r][c] = 0.f;
    const float* Bp = Bm + c0 + cg * 4;
    for (int k0 = 0; k0 < 512; k0 += 32) {
        __syncthreads();
        float4 av = *(const float4*)(Ap + k0 + k4);
        sAT[(k4 + 0) * 34 + lrow] = av.x;
        sAT[(k4 + 1) * 34 + lrow] = av.y;
        sAT[(k4 + 2) * 34 + lrow] = av.z;
        sAT[(k4 + 3) * 34 + lrow] = av.w;
        __syncthreads();
#pragma unroll 8
        for (int kk = 0; kk < 32; kk++) {
            float a0 = sAT[kk * 34 + rg * 2];
            float a1 = sAT[kk * 34 + rg * 2 + 1];
            float4 bv = *(const float4*)(Bp + (k0 + kk) * 512);
            acc[0][0] = fmaf(a0, bv.x, acc[0][0]); acc[0][1] = fmaf(a0, bv.y, acc[0][1]);
            acc[0][2] = fmaf(a0, bv.z, acc[0][2]); acc[0][3] = fmaf(a0, bv.w, acc[0][3]);
            acc[1][0] = fmaf(a1, bv.x, acc[1][0]); acc[1][1] = fmaf(a1, bv.y, acc[1][1]);
            acc[1][2] = fmaf(a1, bv.z, acc[1][2]); acc[1][3] = fmaf(a1, bv.w, acc[1][3]);
        }
    }
    int rr = r0 + rg * 2, cc = c0 + cg * 4;
#pragma unroll
    for (int r = 0; r < 2; r++) {
        if (BF16OUT) {
            unsigned long long pk =
                (unsigned long long)f2bf(acc[r][0]) | ((unsigned long long)f2bf(acc[r][1]) << 16) |
                ((unsigned long long)f2bf(acc[r][2]) << 32) | ((unsigned long long)f2bf(acc[r][3]) << 48);
            *(unsigned long long*)(Cb + (rr + r) * 512 + cc) = pk;
        } else {
            *(float4*)(Cf + (rr + r) * 512 + cc) = make_float4(acc[r][0], acc[r][1], acc[r][2], acc[r][3]);
        }
    }
}

// ---- prep: [0,256) sims(4 imgs) | [256,512) U | [512,560) T | [560,576) W2Tf ---
__global__ __launch_bounds__(256) void prep_kernel(
    const float* __restrict__ img, const float* __restrict__ tn,
    const float* __restrict__ ta, const float* __restrict__ ls,
    const float* __restrict__ W1, const float* __restrict__ W2,
    float* __restrict__ e_ws, float* __restrict__ U_ws,
    unsigned short* __restrict__ Tb, unsigned short* __restrict__ W2Tf) {
    __shared__ __align__(16) float smem[8704];
    int idx = blockIdx.x;
    int t = threadIdx.x;

    if (idx < 256) {
        int bi0 = idx * 4;
        float* sImg = smem;             // 4 x 516
        float* sS   = smem + 2064;      // 4 x 192
        float* sMx  = smem + 2832;      // 8
        float* sSum = smem + 2840;      // 8
#pragma unroll
        for (int p = 0; p < 2; p++) {
            int i4 = t + 256 * p;
            int i = i4 >> 7, k4 = (i4 & 127) * 4;
            float4 v = *(const float4*)(img + (bi0 + i) * 512 + k4);
            sImg[i * 516 + k4 + 0] = v.x; sImg[i * 516 + k4 + 1] = v.y;
            sImg[i * 516 + k4 + 2] = v.z; sImg[i * 516 + k4 + 3] = v.w;
        }
        __syncthreads();
        float scale = __expf(ls[0]);
        int i = t & 3, n0 = (t >> 2) * 3;
        const float* txp[3];
#pragma unroll
        for (int r = 0; r < 3; r++) {
            int n = n0 + r;
            txp[r] = (n < 96) ? (tn + n * 512) : (ta + (n - 96) * 512);
        }
        float d0 = 0.f, d1 = 0.f, d2 = 0.f;
        const float* ib = &sImg[i * 516];
#pragma unroll 4
        for (int k4 = 0; k4 < 512; k4 += 4) {
            float4 iv = *(const float4*)(ib + k4);
            float4 a = *(const float4*)(txp[0] + k4);
            float4 b = *(const float4*)(txp[1] + k4);
            float4 c = *(const float4*)(txp[2] + k4);
            d0 += iv.x * a.x + iv.y * a.y + iv.z * a.z + iv.w * a.w;
            d1 += iv.x * b.x + iv.y * b.y + iv.z * b.z + iv.w * b.w;
            d2 += iv.x * c.x + iv.y * c.y + iv.z * c.z + iv.w * c.w;
        }
        sS[i * 192 + n0 + 0] = d0 * scale;
        sS[i * 192 + n0 + 1] = d1 * scale;
        sS[i * 192 + n0 + 2] = d2 * scale;
        __syncthreads();
        if (t < 8) {
            int ii = t >> 1, brx = t & 1;
            const float* base = &sS[ii * 192 + brx * 96];
            float m = -1e30f;
            for (int n = 0; n < 96; n++) m = fmaxf(m, base[n]);
            float s = 0.f;
            for (int n = 0; n < 96; n++) s += __expf(base[n] - m);
            sMx[t] = m; sSum[t] = s;
        }
        __syncthreads();
#pragma unroll
        for (int p = 0; p < 3; p++) {
            int j = t + 256 * p;
            int ii = j & 3, n = j >> 2;
            int brx = (n >= 96) ? 1 : 0;
            int nn = n - brx * 96;
            float w = __expf(sS[ii * 192 + n] - sMx[ii * 2 + brx]) / sSum[ii * 2 + brx];
            e_ws[(brx * 1024 + bi0 + ii) * 96 + nn] = __expf(w);
        }
    } else if (idx < 512) {
        int i2 = idx - 256;
        gemm32<false>(img, img, 1 << 20, W1, U_ws, nullptr, i2 >> 3, i2 & 7, smem, t);
    } else if (idx < 560) {
        int i2 = idx - 512;
        gemm32<true>(tn, ta, 96, W1 + 512 * 512, nullptr, Tb, i2 >> 3, i2 & 7, smem, t);
    } else {
        // W2 [512][256] -> W2Tf[((kt*16+nt)*64+lane)*8+jj] = bf16(W2[kt*32+(lane>>4)*8+jj][nt*16+(lane&15)])
        int kt = idx - 560;
        int k0 = kt * 32;
        float* sWT = smem;                // [256][33]
        int kr = t >> 3, n0 = (t & 7) * 32;
#pragma unroll
        for (int c = 0; c < 8; c++) {
            float4 v = *(const float4*)(W2 + (k0 + kr) * 256 + n0 + c * 4);
            sWT[(n0 + c * 4 + 0) * 33 + kr] = v.x;
            sWT[(n0 + c * 4 + 1) * 33 + kr] = v.y;
            sWT[(n0 + c * 4 + 2) * 33 + kr] = v.z;
            sWT[(n0 + c * 4 + 3) * 33 + kr] = v.w;
        }
        __syncthreads();
        int lane = t & 63;
        int kl = (lane >> 4) * 8;
#pragma unroll
        for (int it = 0; it < 4; it++) {
            int nt = it * 4 + (t >> 6);
            int n = nt * 16 + (lane & 15);
            uint4v u;
#pragma unroll
            for (int c = 0; c < 4; c++) {
                unsigned short lo = f2bf(sWT[n * 33 + kl + 2 * c]);
                unsigned short hi = f2bf(sWT[n * 33 + kl + 2 * c + 1]);
                u[c] = (unsigned int)lo | ((unsigned int)hi << 16);
            }
            *(uint4v*)(W2Tf + (((kt * 16 + nt) * 64) + lane) * 8) = u;
        }
    }
}

// ---- branch_mlp7: loads at top of region; stage at bottom; 1 barrier/region ----
// grid (1024, 2, 2), block 256 (4 waves x 64 cols). 48 rows, K=512, BK=64.
__global__ __launch_bounds__(256, 4) void branch_mlp7(
    const float* __restrict__ U, const unsigned short* __restrict__ Tb,
    const float* __restrict__ e_all, const unsigned short* __restrict__ W2Tf,
    const float* __restrict__ b1, const float* __restrict__ b2,
    float* __restrict__ m2p) {
    int b = blockIdx.x, br = blockIdx.y, half = blockIdx.z;
    const unsigned short* T = Tb + br * (96 * 512) + half * (48 * 512);

    __shared__ float sUb[512];
    __shared__ float sE[48];
    __shared__ __align__(16) unsigned short sH[2][48 * 64];

    int t = threadIdx.x;
    sUb[t] = U[b * 512 + t] + b1[t];
    sUb[t + 256] = U[b * 512 + t + 256] + b1[t + 256];
    if (t < 48) sE[t] = e_all[(br * 1024 + b) * 96 + half * 48 + t];

    const int wave = t >> 6, lane = t & 63;
    const int frow = lane & 15, fkq = (lane >> 4) * 8;
    const int f7 = frow & 7;
    const int srow = t >> 3;          // 0..31
    const int skc = (t & 7) * 8;      // 0..56
    const bool two = (t < 128);       // waves 0,1 also stage rows 32..47
    const int srow2 = 32 + (t >> 3);
    const int sw1 = skc ^ ((srow & 7) * 8);
    const int sw2 = skc ^ ((srow2 & 7) * 8);
    const int ka0 = (((fkq >> 3) ^ f7) << 3);
    const int ka1 = (((4 + (fkq >> 3)) ^ f7) << 3);

    const floatx4 fz = {0.f, 0.f, 0.f, 0.f};
    floatx4 acc[3][4];
#pragma unroll
    for (int mt = 0; mt < 3; mt++)
#pragma unroll
        for (int j = 0; j < 4; j++) acc[mt][j] = fz;

    // tile-0 T rows + kt=0 B-frags, issued before first barrier
    short8 tv0 = *(const short8*)(T + srow * 512 + skc);
    short8 tv1 = two ? *(const short8*)(T + srow2 * 512 + skc) : tv0;
    const unsigned short* Wf = W2Tf + (wave * 4 * 64 + lane) * 8;
    short8 bpre[4];
#pragma unroll
    for (int j = 0; j < 4; j++)
        bpre[j] = *(const short8*)(Wf + j * (64 * 8));

    __syncthreads();   // sUb/sE ready

    float ev0 = sE[srow];
    float ev1 = two ? sE[srow2] : 0.f;

    // ---- stage tile 0 ----
    {
        float4 u0 = *(const float4*)(&sUb[skc]);
        float4 u1 = *(const float4*)(&sUb[skc + 4]);
        float ua[8] = {u0.x, u0.y, u0.z, u0.w, u1.x, u1.y, u1.z, u1.w};
        uint4v pk;
#pragma unroll
        for (int jj = 0; jj < 4; jj++) {
            float f0 = fmaxf(fmaf(ev0, bf2f((unsigned short)tv0[2 * jj]), ua[2 * jj]), 0.f);
            float f1 = fmaxf(fmaf(ev0, bf2f((unsigned short)tv0[2 * jj + 1]), ua[2 * jj + 1]), 0.f);
            __hip_bfloat162 h2 = __float22bfloat162_rn(make_float2(f0, f1));
            unsigned int bits; __builtin_memcpy(&bits, &h2, 4);
            pk[jj] = bits;
        }
        *(uint4v*)(&sH[0][srow * 64 + sw1]) = pk;
        if (two) {
            uint4v pk2;
#pragma unroll
            for (int jj = 0; jj < 4; jj++) {
                float f0 = fmaxf(fmaf(ev1, bf2f((unsigned short)tv1[2 * jj]), ua[2 * jj]), 0.f);
                float f1 = fmaxf(fmaf(ev1, bf2f((unsigned short)tv1[2 * jj + 1]), ua[2 * jj + 1]), 0.f);
                __hip_bfloat162 h2 = __float22bfloat162_rn(make_float2(f0, f1));
                unsigned int bits; __builtin_memcpy(&bits, &h2, 4);
                pk2[jj] = bits;
            }
            *(uint4v*)(&sH[0][srow2 * 64 + sw2]) = pk2;
        }
    }

#pragma unroll
    for (int s = 0; s < 8; s++) {
        int k0 = s * 64;
        unsigned short* sHb = sH[s & 1];
        __syncthreads();   // sH[s&1] ready (single barrier per region)

        // ---- issue ALL loads for this + next region, right after barrier ----
        short8 b1f[4];
#pragma unroll
        for (int j = 0; j < 4; j++)
            b1f[j] = *(const short8*)(Wf + ((2 * s + 1) * 16 + j) * (64 * 8));
        if (s < 7) {
            tv0 = *(const short8*)(T + srow * 512 + k0 + 64 + skc);
            if (two) tv1 = *(const short8*)(T + srow2 * 512 + k0 + 64 + skc);
        }
        short8 bnext[4];
        if (s < 7) {
#pragma unroll
            for (int j = 0; j < 4; j++)
                bnext[j] = *(const short8*)(Wf + ((2 * s + 2) * 16 + j) * (64 * 8));
        }

        // ---- MFMA ks=0 (bpre in regs) ----
#pragma unroll
        for (int mt = 0; mt < 3; mt++) {
            short8 afr = *(const short8*)(&sHb[(mt * 16 + frow) * 64 + ka0]);
#pragma unroll
            for (int j = 0; j < 4; j++)
                acc[mt][j] = __builtin_amdgcn_mfma_f32_16x16x32_bf16(afr, bpre[j], acc[mt][j], 0, 0, 0);
        }
        // ---- MFMA ks=1 (b1f had 12 MFMAs of slack) ----
#pragma unroll
        for (int mt = 0; mt < 3; mt++) {
            short8 afr = *(const short8*)(&sHb[(mt * 16 + frow) * 64 + ka1]);
#pragma unroll
            for (int j = 0; j < 4; j++)
                acc[mt][j] = __builtin_amdgcn_mfma_f32_16x16x32_bf16(afr, b1f[j], acc[mt][j], 0, 0, 0);
        }
#pragma unroll
        for (int j = 0; j < 4; j++) bpre[j] = bnext[j];

        // ---- stage tile s+1 at bottom of region (tv had full MFMA window) ----
        if (s < 7) {
            unsigned short* sHn = sH[(s + 1) & 1];
            float4 u0 = *(const float4*)(&sUb[k0 + 64 + skc]);
            float4 u1 = *(const float4*)(&sUb[k0 + 64 + skc + 4]);
            float ua[8] = {u0.x, u0.y, u0.z, u0.w, u1.x, u1.y, u1.z, u1.w};
            uint4v pk;
#pragma unroll
            for (int jj = 0; jj < 4; jj++) {
                float f0 = fmaxf(fmaf(ev0, bf2f((unsigned short)tv0[2 * jj]), ua[2 * jj]), 0.f);
                float f1 = fmaxf(fmaf(ev0, bf2f((unsigned short)tv0[2 * jj + 1]), ua[2 * jj + 1]), 0.f);
                __hip_bfloat162 h2 = __float22bfloat162_rn(make_float2(f0, f1));
                unsigned int bits; __builtin_memcpy(&bits, &h2, 4);
                pk[jj] = bits;
            }
            *(uint4v*)(&sHn[srow * 64 + sw1]) = pk;
            if (two) {
                uint4v pk2;
#pragma unroll
                for (int jj = 0; jj < 4; jj++) {
                    float f0 = fmaxf(fmaf(ev1, bf2f((unsigned short)tv1[2 * jj]), ua[2 * jj]), 0.f);
                    float f1 = fmaxf(fmaf(ev1, bf2f((unsigned short)tv1[2 * jj + 1]), ua[2 * jj + 1]), 0.f);
                    __hip_bfloat162 h2 = __float22bfloat162_rn(make_float2(f0, f1));
                    unsigned int bits; __builtin_memcpy(&bits, &h2, 4);
                    pk2[jj] = bits;
                }
                *(uint4v*)(&sHn[srow2 * 64 + sw2]) = pk2;
            }
        }
    }

    // epilogue: +b2, relu, partial sum over 48 rows -> m2p[half*2+br][b][256]
#pragma unroll
    for (int j = 0; j < 4; j++) {
        int col = wave * 64 + j * 16 + frow;
        float bb = b2[col];
        float s = 0.f;
#pragma unroll
        for (int mt = 0; mt < 3; mt++)
#pragma unroll
            for (int r = 0; r < 4; r++)
                s += fmaxf(acc[mt][j][r] + bb, 0.f);
        s += __shfl_xor(s, 16);
        s += __shfl_xor(s, 32);
        if (lane < 16)
            m2p[(((half * 2 + br) * 1024) + b) * 256 + col] = s;
    }
}

// ---- out_kernel: m2 = (p0+p1)/96; out = m2@W3 + b3 ----------------------------
__global__ __launch_bounds__(128) void out_kernel(
    const float* __restrict__ m2p, const float* __restrict__ W3,
    const float* __restrict__ b3, float* __restrict__ out) {
    int b = blockIdx.x, br = blockIdx.y;
    int t = threadIdx.x;
    __shared__ float sM[256];
    const float* p0 = m2p + ((0 + br) * 1024 + b) * 256;
    const float* p1 = m2p + ((2 + br) * 1024 + b) * 256;
    sM[t]       = (p0[t]       + p1[t])       * (1.0f / 96.0f);
    sM[t + 128] = (p0[t + 128] + p1[t + 128]) * (1.0f / 96.0f);
    __syncthreads();
    float o = b3[t];
#pragma unroll 8
    for (int k = 0; k < 256; k++) o = fmaf(sM[k], W3[k * 128 + t], o);
    out[(br * 1024 + b) * 128 + t] = o;
}

// ---- launch --------------------------------------------------------------------
extern "C" void kernel_launch(void* const* d_in, const int* in_sizes, int n_in,
                              void* d_out, int out_size, void* d_ws, size_t ws_size,
                              hipStream_t stream) {
    const float* img = (const float*)d_in[0];
    const float* tn  = (const float*)d_in[1];
    const float* ta  = (const float*)d_in[2];
    const float* ls  = (const float*)d_in[3];
    const float* W1  = (const float*)d_in[4];
    const float* b1  = (const float*)d_in[5];
    const float* W2  = (const float*)d_in[6];
    const float* b2  = (const float*)d_in[7];
    const float* W3  = (const float*)d_in[8];
    const float* b3  = (const float*)d_in[9];
    float* out = (float*)d_out;
    float* ws  = (float*)d_ws;

    float* e_ws = ws;                                        // 196608 f
    float* U_ws = ws + 196608;                               // 524288 f
    unsigned short* Tb   = (unsigned short*)(ws + 720896);   // 192*512 bf16
    unsigned short* W2Tf = (unsigned short*)(ws + 770048);   // 256*512 bf16 frag layout
    float* m2p = ws + 835584;                                // 4*1024*256 f

    prep_kernel<<<576, 256, 0, stream>>>(img, tn, ta, ls, W1, W2, e_ws, U_ws, Tb, W2Tf);
    branch_mlp7<<<dim3(1024, 2, 2), 256, 0, stream>>>(U_ws, Tb, e_ws, W2Tf, b1, b2, m2p);
    out_kernel<<<dim3(1024, 2), 128, 0, stream>>>(m2p, W3, b3, out);
}

// Round 8
// 176.536 us; speedup vs baseline: 1.2059x; 1.0601x over previous
//
#include <hip/hip_runtime.h>
#include <hip/hip_bf16.h>

// B=1024, N=96/branch, D=512.
// h1[b,n,:] = relu(U[b] + e[b,n]*T[n] + b1);  U=img@W1[:512], T=text@W1[512:]
// m2[b] = mean_n relu(h1@W2 + b2);  out = m2@W3 + b3
// prep (576 blk): sims | U gemm | T gemm(bf16) | W2 -> MFMA-B-fragment layout bf16.
// branch_mlp8: R=96 (full branch per block, grid 1024x2), C=256; halves B-L2
//   traffic; pk-f32 staging math; fused mean+W3 epilogue (no out_kernel).

typedef __attribute__((ext_vector_type(8))) short short8;
typedef __attribute__((ext_vector_type(4))) float floatx4;
typedef __attribute__((ext_vector_type(2))) float float2v;
typedef __attribute__((ext_vector_type(4))) unsigned int uint4v;

__device__ __forceinline__ unsigned short f2bf(float x) {
    unsigned int u = __float_as_uint(x);
    u += 0x7fffu + ((u >> 16) & 1u);   // RNE
    return (unsigned short)(u >> 16);
}
__device__ __forceinline__ float bf2f(unsigned short u) {
    return __uint_as_float(((unsigned int)u) << 16);
}

// ---- 32x64-tile fp32 GEMM (K=512): C[32 rows][64 cols], LDS sAT[32][34] -------
template <bool BF16OUT>
__device__ __forceinline__ void gemm32(
    const float* __restrict__ A0, const float* __restrict__ A1, int rows0,
    const float* __restrict__ Bm, float* __restrict__ Cf,
    unsigned short* __restrict__ Cb, int mt, int nt, float* sAT, int t) {
    int r0 = mt * 32, c0 = nt * 64;
    int rg = t >> 4, cg = t & 15;
    int lrow = t >> 3, k4 = (t & 7) * 4;
    int gr = r0 + lrow;
    const float* Ap = (gr < rows0) ? (A0 + gr * 512) : (A1 + (gr - rows0) * 512);
    float acc[2][4];
#pragma unroll
    for (int r = 0; r < 2; r++)
#pragma unroll
        for (int c = 0; c < 4; c++) acc[r][c] = 0.f;
    const float* Bp = Bm + c0 + cg * 4;
    for (int k0 = 0; k0 < 512; k0 += 32) {
        __syncthreads();
        float4 av = *(const float4*)(Ap + k0 + k4);
        sAT[(k4 + 0) * 34 + lrow] = av.x;
        sAT[(k4 + 1) * 34 + lrow] = av.y;
        sAT[(k4 + 2) * 34 + lrow] = av.z;
        sAT[(k4 + 3) * 34 + lrow] = av.w;
        __syncthreads();
#pragma unroll 8
        for (int kk = 0; kk < 32; kk++) {
            float a0 = sAT[kk * 34 + rg * 2];
            float a1 = sAT[kk * 34 + rg * 2 + 1];
            float4 bv = *(const float4*)(Bp + (k0 + kk) * 512);
            acc[0][0] = fmaf(a0, bv.x, acc[0][0]); acc[0][1] = fmaf(a0, bv.y, acc[0][1]);
            acc[0][2] = fmaf(a0, bv.z, acc[0][2]); acc[0][3] = fmaf(a0, bv.w, acc[0][3]);
            acc[1][0] = fmaf(a1, bv.x, acc[1][0]); acc[1][1] = fmaf(a1, bv.y, acc[1][1]);
            acc[1][2] = fmaf(a1, bv.z, acc[1][2]); acc[1][3] = fmaf(a1, bv.w, acc[1][3]);
        }
    }
    int rr = r0 + rg * 2, cc = c0 + cg * 4;
#pragma unroll
    for (int r = 0; r < 2; r++) {
        if (BF16OUT) {
            unsigned long long pk =
                (unsigned long long)f2bf(acc[r][0]) | ((unsigned long long)f2bf(acc[r][1]) << 16) |
                ((unsigned long long)f2bf(acc[r][2]) << 32) | ((unsigned long long)f2bf(acc[r][3]) << 48);
            *(unsigned long long*)(Cb + (rr + r) * 512 + cc) = pk;
        } else {
            *(float4*)(Cf + (rr + r) * 512 + cc) = make_float4(acc[r][0], acc[r][1], acc[r][2], acc[r][3]);
        }
    }
}

// ---- prep: [0,256) sims(4 imgs) | [256,512) U | [512,560) T | [560,576) W2Tf ---
__global__ __launch_bounds__(256) void prep_kernel(
    const float* __restrict__ img, const float* __restrict__ tn,
    const float* __restrict__ ta, const float* __restrict__ ls,
    const float* __restrict__ W1, const float* __restrict__ W2,
    float* __restrict__ e_ws, float* __restrict__ U_ws,
    unsigned short* __restrict__ Tb, unsigned short* __restrict__ W2Tf) {
    __shared__ __align__(16) float smem[8704];
    int idx = blockIdx.x;
    int t = threadIdx.x;

    if (idx < 256) {
        int bi0 = idx * 4;
        float* sImg = smem;             // 4 x 516
        float* sS   = smem + 2064;      // 4 x 192
        float* sMx  = smem + 2832;      // 8
        float* sSum = smem + 2840;      // 8
#pragma unroll
        for (int p = 0; p < 2; p++) {
            int i4 = t + 256 * p;
            int i = i4 >> 7, k4 = (i4 & 127) * 4;
            float4 v = *(const float4*)(img + (bi0 + i) * 512 + k4);
            sImg[i * 516 + k4 + 0] = v.x; sImg[i * 516 + k4 + 1] = v.y;
            sImg[i * 516 + k4 + 2] = v.z; sImg[i * 516 + k4 + 3] = v.w;
        }
        __syncthreads();
        float scale = __expf(ls[0]);
        int i = t & 3, n0 = (t >> 2) * 3;
        const float* txp[3];
#pragma unroll
        for (int r = 0; r < 3; r++) {
            int n = n0 + r;
            txp[r] = (n < 96) ? (tn + n * 512) : (ta + (n - 96) * 512);
        }
        float d0 = 0.f, d1 = 0.f, d2 = 0.f;
        const float* ib = &sImg[i * 516];
#pragma unroll 4
        for (int k4 = 0; k4 < 512; k4 += 4) {
            float4 iv = *(const float4*)(ib + k4);
            float4 a = *(const float4*)(txp[0] + k4);
            float4 b = *(const float4*)(txp[1] + k4);
            float4 c = *(const float4*)(txp[2] + k4);
            d0 += iv.x * a.x + iv.y * a.y + iv.z * a.z + iv.w * a.w;
            d1 += iv.x * b.x + iv.y * b.y + iv.z * b.z + iv.w * b.w;
            d2 += iv.x * c.x + iv.y * c.y + iv.z * c.z + iv.w * c.w;
        }
        sS[i * 192 + n0 + 0] = d0 * scale;
        sS[i * 192 + n0 + 1] = d1 * scale;
        sS[i * 192 + n0 + 2] = d2 * scale;
        __syncthreads();
        if (t < 8) {
            int ii = t >> 1, brx = t & 1;
            const float* base = &sS[ii * 192 + brx * 96];
            float m = -1e30f;
            for (int n = 0; n < 96; n++) m = fmaxf(m, base[n]);
            float s = 0.f;
            for (int n = 0; n < 96; n++) s += __expf(base[n] - m);
            sMx[t] = m; sSum[t] = s;
        }
        __syncthreads();
#pragma unroll
        for (int p = 0; p < 3; p++) {
            int j = t + 256 * p;
            int ii = j & 3, n = j >> 2;
            int brx = (n >= 96) ? 1 : 0;
            int nn = n - brx * 96;
            float w = __expf(sS[ii * 192 + n] - sMx[ii * 2 + brx]) / sSum[ii * 2 + brx];
            e_ws[(brx * 1024 + bi0 + ii) * 96 + nn] = __expf(w);
        }
    } else if (idx < 512) {
        int i2 = idx - 256;
        gemm32<false>(img, img, 1 << 20, W1, U_ws, nullptr, i2 >> 3, i2 & 7, smem, t);
    } else if (idx < 560) {
        int i2 = idx - 512;
        gemm32<true>(tn, ta, 96, W1 + 512 * 512, nullptr, Tb, i2 >> 3, i2 & 7, smem, t);
    } else {
        // W2 [512][256] -> W2Tf[((kt*16+nt)*64+lane)*8+jj] = bf16(W2[kt*32+(lane>>4)*8+jj][nt*16+(lane&15)])
        int kt = idx - 560;
        int k0 = kt * 32;
        float* sWT = smem;                // [256][33]
        int kr = t >> 3, n0 = (t & 7) * 32;
#pragma unroll
        for (int c = 0; c < 8; c++) {
            float4 v = *(const float4*)(W2 + (k0 + kr) * 256 + n0 + c * 4);
            sWT[(n0 + c * 4 + 0) * 33 + kr] = v.x;
            sWT[(n0 + c * 4 + 1) * 33 + kr] = v.y;
            sWT[(n0 + c * 4 + 2) * 33 + kr] = v.z;
            sWT[(n0 + c * 4 + 3) * 33 + kr] = v.w;
        }
        __syncthreads();
        int lane = t & 63;
        int kl = (lane >> 4) * 8;
#pragma unroll
        for (int it = 0; it < 4; it++) {
            int nt = it * 4 + (t >> 6);
            int n = nt * 16 + (lane & 15);
            uint4v u;
#pragma unroll
            for (int c = 0; c < 4; c++) {
                unsigned short lo = f2bf(sWT[n * 33 + kl + 2 * c]);
                unsigned short hi = f2bf(sWT[n * 33 + kl + 2 * c + 1]);
                u[c] = (unsigned int)lo | ((unsigned int)hi << 16);
            }
            *(uint4v*)(W2Tf + (((kt * 16 + nt) * 64) + lane) * 8) = u;
        }
    }
}

// ---- pk-f32 staging of one row-k-chunk: 8 bf16 T elems -> 8 bf16 h1 elems -----
__device__ __forceinline__ uint4v stage8(float ev, short8 tv, const float2v* u2) {
    uint4v tp; __builtin_memcpy(&tp, &tv, 16);
    float2v e2 = {ev, ev};
    const float2v z2 = {0.f, 0.f};
    uint4v pk;
#pragma unroll
    for (int jj = 0; jj < 4; jj++) {
        float2v t2;
        t2.x = __uint_as_float(tp[jj] << 16);
        t2.y = __uint_as_float(tp[jj] & 0xffff0000u);
        float2v f = __builtin_elementwise_fma(e2, t2, u2[jj]);
        f = __builtin_elementwise_max(f, z2);
        __hip_bfloat162 h2 = __float22bfloat162_rn(make_float2(f.x, f.y));
        unsigned int bits; __builtin_memcpy(&bits, &h2, 4);
        pk[jj] = bits;
    }
    return pk;
}

// ---- branch_mlp8: R=96, C=256, fused mean+W3 epilogue --------------------------
// grid (1024, 2), block 256 (4 waves x 64 cols). K=512, BK=64, dbuf, 1 barrier.
__global__ __launch_bounds__(256, 3) void branch_mlp8(
    const float* __restrict__ U, const unsigned short* __restrict__ Tb,
    const float* __restrict__ e_all, const unsigned short* __restrict__ W2Tf,
    const float* __restrict__ b1, const float* __restrict__ b2,
    const float* __restrict__ W3, const float* __restrict__ b3,
    float* __restrict__ out) {
    int b = blockIdx.x, br = blockIdx.y;
    const unsigned short* T = Tb + br * (96 * 512);

    __shared__ float sUb[512];
    __shared__ float sE[96];
    __shared__ __align__(16) unsigned short sH[2][96 * 64];
    __shared__ float sM2[256];
    __shared__ float sPart[256];

    int t = threadIdx.x;
    sUb[t] = U[b * 512 + t] + b1[t];
    sUb[t + 256] = U[b * 512 + t + 256] + b1[t + 256];
    if (t < 96) sE[t] = e_all[(br * 1024 + b) * 96 + t];

    const int wave = t >> 6, lane = t & 63;
    const int frow = lane & 15, fkq = (lane >> 4) * 8;
    const int f7 = frow & 7;
    const int srow = t >> 3;          // 0..31
    const int skc = (t & 7) * 8;      // 0..56
    const int sw = skc ^ ((srow & 7) * 8);   // same for srow, srow+32, srow+64
    const int ka0 = (((fkq >> 3) ^ f7) << 3);
    const int ka1 = (((4 + (fkq >> 3)) ^ f7) << 3);

    const floatx4 fz = {0.f, 0.f, 0.f, 0.f};
    floatx4 acc[6][4];
#pragma unroll
    for (int mt = 0; mt < 6; mt++)
#pragma unroll
        for (int j = 0; j < 4; j++) acc[mt][j] = fz;

    // tile-0 T rows + kt=0 B-frags, issued before first barrier
    short8 tv[3];
#pragma unroll
    for (int i2 = 0; i2 < 3; i2++)
        tv[i2] = *(const short8*)(T + (srow + 32 * i2) * 512 + skc);
    const unsigned short* Wf = W2Tf + (wave * 4 * 64 + lane) * 8;
    short8 bpre[4];
#pragma unroll
    for (int j = 0; j < 4; j++)
        bpre[j] = *(const short8*)(Wf + j * (64 * 8));

    __syncthreads();   // sUb/sE ready

    float ev[3];
#pragma unroll
    for (int i2 = 0; i2 < 3; i2++) ev[i2] = sE[srow + 32 * i2];

    // ---- stage tile 0 ----
    {
        float2v u2[4];
#pragma unroll
        for (int jj = 0; jj < 4; jj++) u2[jj] = *(const float2v*)(&sUb[skc + 2 * jj]);
#pragma unroll
        for (int i2 = 0; i2 < 3; i2++)
            *(uint4v*)(&sH[0][(srow + 32 * i2) * 64 + sw]) = stage8(ev[i2], tv[i2], u2);
    }

#pragma unroll
    for (int s = 0; s < 8; s++) {
        int k0 = s * 64;
        unsigned short* sHb = sH[s & 1];
        __syncthreads();   // sH[s&1] ready (single barrier per region)

        // ---- issue ALL loads for this + next region right after the barrier ----
        short8 b1f[4];
#pragma unroll
        for (int j = 0; j < 4; j++)
            b1f[j] = *(const short8*)(Wf + ((2 * s + 1) * 16 + j) * (64 * 8));
        if (s < 7) {
#pragma unroll
            for (int i2 = 0; i2 < 3; i2++)
                tv[i2] = *(const short8*)(T + (srow + 32 * i2) * 512 + k0 + 64 + skc);
        }
        short8 bnext[4];
        if (s < 7) {
#pragma unroll
            for (int j = 0; j < 4; j++)
                bnext[j] = *(const short8*)(Wf + ((2 * s + 2) * 16 + j) * (64 * 8));
        }

        // ---- MFMA ks=0 (bpre in regs) ----
#pragma unroll
        for (int mt = 0; mt < 6; mt++) {
            short8 afr = *(const short8*)(&sHb[(mt * 16 + frow) * 64 + ka0]);
#pragma unroll
            for (int j = 0; j < 4; j++)
                acc[mt][j] = __builtin_amdgcn_mfma_f32_16x16x32_bf16(afr, bpre[j], acc[mt][j], 0, 0, 0);
        }
        // ---- MFMA ks=1 ----
#pragma unroll
        for (int mt = 0; mt < 6; mt++) {
            short8 afr = *(const short8*)(&sHb[(mt * 16 + frow) * 64 + ka1]);
#pragma unroll
            for (int j = 0; j < 4; j++)
                acc[mt][j] = __builtin_amdgcn_mfma_f32_16x16x32_bf16(afr, b1f[j], acc[mt][j], 0, 0, 0);
        }
#pragma unroll
        for (int j = 0; j < 4; j++) bpre[j] = bnext[j];

        // ---- stage tile s+1 at bottom (tv had the full MFMA window) ----
        if (s < 7) {
            unsigned short* sHn = sH[(s + 1) & 1];
            float2v u2[4];
#pragma unroll
            for (int jj = 0; jj < 4; jj++) u2[jj] = *(const float2v*)(&sUb[k0 + 64 + skc + 2 * jj]);
#pragma unroll
            for (int i2 = 0; i2 < 3; i2++)
                *(uint4v*)(&sHn[(srow + 32 * i2) * 64 + sw]) = stage8(ev[i2], tv[i2], u2);
        }
    }

    // epilogue 1: +b2, relu, mean over 96 rows -> sM2[256]
#pragma unroll
    for (int j = 0; j < 4; j++) {
        int col = wave * 64 + j * 16 + frow;
        float bb = b2[col];
        float s = 0.f;
#pragma unroll
        for (int mt = 0; mt < 6; mt++)
#pragma unroll
            for (int r = 0; r < 4; r++)
                s += fmaxf(acc[mt][j][r] + bb, 0.f);
        s += __shfl_xor(s, 16);
        s += __shfl_xor(s, 32);
        if (lane < 16) sM2[col] = s * (1.0f / 96.0f);
    }
    __syncthreads();

    // epilogue 2: out = sM2 @ W3 + b3  (256x128), K split across two half-blocks
    int col = t & 127, ks2 = t >> 7;
    const float* w3p = W3 + (ks2 * 128) * 128 + col;
    const float* mp = sM2 + ks2 * 128;
    float o = 0.f;
#pragma unroll 8
    for (int k = 0; k < 128; k++) o = fmaf(mp[k], w3p[k * 128], o);
    sPart[t] = o;
    __syncthreads();
    if (t < 128) out[(br * 1024 + b) * 128 + t] = sPart[t] + sPart[t + 128] + b3[t];
}

// ---- launch --------------------------------------------------------------------
extern "C" void kernel_launch(void* const* d_in, const int* in_sizes, int n_in,
                              void* d_out, int out_size, void* d_ws, size_t ws_size,
                              hipStream_t stream) {
    const float* img = (const float*)d_in[0];
    const float* tn  = (const float*)d_in[1];
    const float* ta  = (const float*)d_in[2];
    const float* ls  = (const float*)d_in[3];
    const float* W1  = (const float*)d_in[4];
    const float* b1  = (const float*)d_in[5];
    const float* W2  = (const float*)d_in[6];
    const float* b2  = (const float*)d_in[7];
    const float* W3  = (const float*)d_in[8];
    const float* b3  = (const float*)d_in[9];
    float* out = (float*)d_out;
    float* ws  = (float*)d_ws;

    float* e_ws = ws;                                        // 196608 f
    float* U_ws = ws + 196608;                               // 524288 f
    unsigned short* Tb   = (unsigned short*)(ws + 720896);   // 192*512 bf16
    unsigned short* W2Tf = (unsigned short*)(ws + 770048);   // 256*512 bf16 frag layout

    prep_kernel<<<576, 256, 0, stream>>>(img, tn, ta, ls, W1, W2, e_ws, U_ws, Tb, W2Tf);
    branch_mlp8<<<dim3(1024, 2), 256, 0, stream>>>(U_ws, Tb, e_ws, W2Tf, b1, b2, W3, b3, out);
}